// Round 10
// baseline (425.590 us; speedup 1.0000x reference)
//
#include <hip/hip_runtime.h>
#include <cstdint>
#include <cstddef>

// Problem constants
#define HRES 25
#define WRES 25
#define NBATCH 32
#define TT 625            // tokens per image
#define CD 512            // channels
#define MT 20000          // total tokens = 32*625
#define HD 2048           // FFN hidden
#define NCH 25            // scan chunks
#define CLEN 25           // chunk length (NCH*CLEN == TT)
#define NBC 32            // (b,c) chains per scan block

typedef __attribute__((ext_vector_type(8))) short short8;
typedef __attribute__((ext_vector_type(4))) float f32x4;

typedef const __attribute__((address_space(1))) void* as1cv;
typedef __attribute__((address_space(3))) void* as3v;

__device__ __forceinline__ float bf2f(unsigned short h){
  union { unsigned int u; float f; } w; w.u = ((unsigned int)h) << 16; return w.f;
}
__device__ __forceinline__ unsigned short f2bf(float f){
  union { float f; unsigned int u; } w; w.f = f;
  unsigned int u = w.u + 0x7fffu + ((w.u >> 16) & 1u);
  return (unsigned short)(u >> 16);
}

// XCD-chunked bijective block swizzle (m204): physical block b (round-robins
// XCD = b%8) -> logical tile id contiguous per XCD. Improves per-XCD L2 reuse
// of shared A-row-tiles / B-col-panels.
__device__ __forceinline__ int xcd_swz(int b, int nwg){
  const int q = nwg >> 3, r = nwg & 7;
  const int x = b & 7;
  const int base = (x < r) ? x * (q + 1) : r * (q + 1) + (x - r) * q;
  return base + (b >> 3);
}

// ---------------------------------------------------------------------------
// GEMM core: C[M,N] = A[M,K](bf16) @ Bt[N,K](bf16).  (verified round-6 m97
// structure: 128x128 tile, BK=64, 4 waves 2x2, global_load_lds width-16,
// XOR-swizzled LDS; ~3 blocks/CU give implicit wave-level overlap.)
// EPI: 1 = sigmoid->bf16; 2 = relu^2->bf16; 3 = f2bf(auxf + acc)->bf16;
//      4 = bf(auxb1) + bf(auxb2)*acc -> f32; 5 = plain bf16
// ---------------------------------------------------------------------------
template<int EPI>
__device__ __forceinline__ void gemm_core(short* As, short* Bs,
    const unsigned short* __restrict__ A, const unsigned short* __restrict__ Bt,
    int M, int N, int K, int bid,
    float* __restrict__ Cf, unsigned short* __restrict__ Cb,
    const float* __restrict__ auxf,
    const unsigned short* __restrict__ auxb1, const unsigned short* __restrict__ auxb2)
{
  const int ntile = N >> 7;
  const int tm = bid / ntile;
  const int tn = bid - tm * ntile;
  const int row0 = tm << 7, col0 = tn << 7;
  const int tid = threadIdx.x;
  const int wave = tid >> 6, lane = tid & 63;
  const int wm = wave >> 1, wn = wave & 1;

  const f32x4 fzero = {0.f, 0.f, 0.f, 0.f};
  f32x4 acc[4][4];
#pragma unroll
  for (int m = 0; m < 4; ++m)
#pragma unroll
    for (int n = 0; n < 4; ++n) acc[m][n] = fzero;

  // staging geometry: chunk = 16B unit; physical chunk p holds logical col (p&7)^(row&7)
  int sr_[4], sc_[4];
#pragma unroll
  for (int s = 0; s < 4; ++s) {
    int chunk = (wave * 4 + s) * 64 + lane;   // 0..1023
    sr_[s] = chunk >> 3;                      // tile row 0..127
    sc_[s] = (chunk & 7) ^ (sr_[s] & 7);      // logical k-chunk to fetch
  }

  for (int k0 = 0; k0 < K; k0 += 64) {
#pragma unroll
    for (int s = 0; s < 4; ++s) {
      const unsigned short* ga = A  + (size_t)(row0 + sr_[s]) * K + (k0 + sc_[s] * 8);
      const unsigned short* gb = Bt + (size_t)(col0 + sr_[s]) * K + (k0 + sc_[s] * 8);
      __builtin_amdgcn_global_load_lds((as1cv)ga, (as3v)(&As[(wave * 4 + s) * 512]), 16, 0, 0);
      __builtin_amdgcn_global_load_lds((as1cv)gb, (as3v)(&Bs[(wave * 4 + s) * 512]), 16, 0, 0);
    }
    __syncthreads();
#pragma unroll
    for (int kh = 0; kh < 2; ++kh) {
      const int cb = kh * 4 + (lane >> 4);    // logical k-chunk for this quarter-wave
      short8 af[4], bfv[4];
#pragma unroll
      for (int m = 0; m < 4; ++m) {
        int r = wm * 64 + m * 16 + (lane & 15);
        af[m] = *(const short8*)&As[r * 64 + ((cb ^ (r & 7)) << 3)];
      }
#pragma unroll
      for (int n = 0; n < 4; ++n) {
        int r = wn * 64 + n * 16 + (lane & 15);
        bfv[n] = *(const short8*)&Bs[r * 64 + ((cb ^ (r & 7)) << 3)];
      }
#pragma unroll
      for (int m = 0; m < 4; ++m)
#pragma unroll
        for (int n = 0; n < 4; ++n)
          acc[m][n] = __builtin_amdgcn_mfma_f32_16x16x32_bf16(af[m], bfv[n], acc[m][n], 0, 0, 0);
    }
    __syncthreads();
  }

  // C/D layout: col = lane&15, row = (lane>>4)*4 + j   [measured m89]
  const int gr0 = row0 + wm * 64 + ((lane >> 4) << 2);
  const int gc0 = col0 + wn * 64 + (lane & 15);
#pragma unroll
  for (int m = 0; m < 4; ++m) {
#pragma unroll
    for (int n = 0; n < 4; ++n) {
      const int gc = gc0 + n * 16;
#pragma unroll
      for (int j = 0; j < 4; ++j) {
        const int gr = gr0 + m * 16 + j;
        if (gr < M) {
          float val = acc[m][n][j];
          size_t idx = (size_t)gr * N + gc;
          if (EPI == 1) Cb[idx] = f2bf(1.f / (1.f + __expf(-val)));
          else if (EPI == 2) { float r = val > 0.f ? val : 0.f; Cb[idx] = f2bf(r * r); }
          else if (EPI == 3) Cb[idx] = f2bf(auxf[idx] + val);
          else if (EPI == 4) Cf[idx] = bf2f(auxb1[idx]) + bf2f(auxb2[idx]) * val;
          else if (EPI == 5) Cb[idx] = f2bf(val);
        }
      }
    }
  }
}

template<int EPI>
__global__ __launch_bounds__(256, 2)
void gemm_one(const unsigned short* __restrict__ A, const unsigned short* __restrict__ Bt,
              int M, int N, int K,
              float* __restrict__ Cf, unsigned short* __restrict__ Cb,
              const float* __restrict__ auxf,
              const unsigned short* __restrict__ auxb1, const unsigned short* __restrict__ auxb2)
{
  __shared__ short As[8192];
  __shared__ short Bs[8192];
  const int bid = xcd_swz(blockIdx.x, gridDim.x);
  gemm_core<EPI>(As, Bs, A, Bt, M, N, K, bid, Cf, Cb, auxf, auxb1, auxb2);
}

// batched QKV: seg 0: k = xk@WkT (bf16), seg 1: v = xv@WvT (bf16), seg 2: sr = sigmoid(xr@WrT)
struct QkvArgs {
  const unsigned short *xk, *xv, *xr, *WkT, *WvT, *WrT;
  unsigned short *k, *v, *sr;
};
__global__ __launch_bounds__(256, 2)
void gemm_qkv(QkvArgs a)
{
  __shared__ short As[8192];
  __shared__ short Bs[8192];
  const int bid = xcd_swz(blockIdx.x, gridDim.x);
  if (bid < 628)
    gemm_core<5>(As, Bs, a.xk, a.WkT, MT, 512, 512, bid, nullptr, a.k, nullptr, nullptr, nullptr);
  else if (bid < 1256)
    gemm_core<5>(As, Bs, a.xv, a.WvT, MT, 512, 512, bid - 628, nullptr, a.v, nullptr, nullptr, nullptr);
  else
    gemm_core<1>(As, Bs, a.xr, a.WrT, MT, 512, 512, bid - 1256, nullptr, a.sr, nullptr, nullptr, nullptr);
}

// batched FFN: seg 0 (2512 blocks): kk = relu^2(xk2@WkfT) N=2048; seg 1 (628): rffn = sigmoid(xr2@WrfT)
struct FfnArgs {
  const unsigned short *xk2, *xr2, *Wkf, *Wrf;
  unsigned short *kk, *rf;
};
__global__ __launch_bounds__(256, 2)
void gemm_ffn(FfnArgs a)
{
  __shared__ short As[8192];
  __shared__ short Bs[8192];
  const int bid = xcd_swz(blockIdx.x, gridDim.x);
  if (bid < 2512)
    gemm_core<2>(As, Bs, a.xk2, a.Wkf, MT, 2048, 512, bid, nullptr, a.kk, nullptr, nullptr, nullptr);
  else
    gemm_core<1>(As, Bs, a.xr2, a.Wrf, MT, 512, 512, bid - 2512, nullptr, a.rf, nullptr, nullptr, nullptr);
}

// ---------------------------------------------------------------------------
// LayerNorm over 512 -> bf16 out. One wave per token, 4 tokens/block.
// MODE 0: out = LN(in)*g+b ; MODE 1: out = (LN(in)*g+b) * bf(mul)
// BIN 0: f32 input ; BIN 1: bf16 input
// ---------------------------------------------------------------------------
template<int MODE, int BIN>
__global__ __launch_bounds__(256)
void ln512_k(const void* __restrict__ inv, const float* __restrict__ gw, const float* __restrict__ bw,
             const unsigned short* __restrict__ mul, unsigned short* __restrict__ out)
{
  const int tok = blockIdx.x * 4 + (threadIdx.x >> 6);
  const int lane = threadIdx.x & 63;
  const size_t base = (size_t)tok * CD + lane * 8;
  f32x4 v0, v1;
  if (BIN) {
    short8 h = *(const short8*)((const unsigned short*)inv + base);
#pragma unroll
    for (int j = 0; j < 4; ++j) { v0[j] = bf2f((unsigned short)h[j]); v1[j] = bf2f((unsigned short)h[4 + j]); }
  } else {
    v0 = *(const f32x4*)((const float*)inv + base);
    v1 = *(const f32x4*)((const float*)inv + base + 4);
  }
  float s = (v0[0] + v0[1]) + (v0[2] + v0[3]) + (v1[0] + v1[1]) + (v1[2] + v1[3]);
#pragma unroll
  for (int o = 32; o; o >>= 1) s += __shfl_xor(s, o, 64);
  const float mean = s * (1.f / 512.f);
  float q = 0.f;
#pragma unroll
  for (int j = 0; j < 4; ++j) { float d = v0[j] - mean; q += d * d; d = v1[j] - mean; q += d * d; }
#pragma unroll
  for (int o = 32; o; o >>= 1) q += __shfl_xor(q, o, 64);
  const float rstd = rsqrtf(q * (1.f / 512.f) + 1e-5f);
  const int c = lane * 8;
  f32x4 ga = *(const f32x4*)(gw + c), gb = *(const f32x4*)(gw + c + 4);
  f32x4 ba = *(const f32x4*)(bw + c), bb = *(const f32x4*)(bw + c + 4);
  float mv[8];
  if (MODE == 1) {
    short8 m8 = *(const short8*)(mul + base);
#pragma unroll
    for (int j = 0; j < 8; ++j) mv[j] = bf2f((unsigned short)m8[j]);
  }
  short8 o8;
#pragma unroll
  for (int j = 0; j < 4; ++j) {
    float r0 = (v0[j] - mean) * rstd * ga[j] + ba[j];
    float r1 = (v1[j] - mean) * rstd * gb[j] + bb[j];
    if (MODE == 1) { r0 *= mv[j]; r1 *= mv[4 + j]; }
    o8[j]     = (short)f2bf(r0);
    o8[4 + j] = (short)f2bf(r1);
  }
  *(short8*)(out + base) = o8;
}

// LayerNorm over 2048 bf16, in-place. One wave per token, 4 tokens/block.
__global__ __launch_bounds__(256)
void ln2048_k(unsigned short* __restrict__ buf, const float* __restrict__ gw, const float* __restrict__ bw)
{
  const int tok = blockIdx.x * 4 + (threadIdx.x >> 6);
  const int lane = threadIdx.x & 63;
  unsigned short* p = buf + (size_t)tok * HD;
  float vals[32];
  float s = 0.f;
#pragma unroll
  for (int jb = 0; jb < 4; ++jb) {
    short8 h = *(const short8*)(p + jb * 512 + lane * 8);
#pragma unroll
    for (int j = 0; j < 8; ++j) { float f = bf2f((unsigned short)h[j]); vals[jb * 8 + j] = f; s += f; }
  }
#pragma unroll
  for (int o = 32; o; o >>= 1) s += __shfl_xor(s, o, 64);
  const float mean = s * (1.f / 2048.f);
  float q = 0.f;
#pragma unroll
  for (int i = 0; i < 32; ++i) { float d = vals[i] - mean; q += d * d; }
#pragma unroll
  for (int o = 32; o; o >>= 1) q += __shfl_xor(q, o, 64);
  const float rstd = rsqrtf(q * (1.f / 2048.f) + 1e-5f);
#pragma unroll
  for (int jb = 0; jb < 4; ++jb) {
    const int c = jb * 512 + lane * 8;
    f32x4 ga = *(const f32x4*)(gw + c), gb = *(const f32x4*)(gw + c + 4);
    f32x4 ba = *(const f32x4*)(bw + c), bb = *(const f32x4*)(bw + c + 4);
    short8 o8;
#pragma unroll
    for (int j = 0; j < 4; ++j) {
      o8[j]     = (short)f2bf((vals[jb * 8 + j]     - mean) * rstd * ga[j] + ba[j]);
      o8[4 + j] = (short)f2bf((vals[jb * 8 + 4 + j] - mean) * rstd * gb[j] + bb[j]);
    }
    *(short8*)(p + c) = o8;
  }
}

// ---------------------------------------------------------------------------
// q_shift + token-mix: out_i = xn*m_i + xx*(1-m_i). 4 tokens per 256-thr block.
// channel group g = c>>7 : 0:(h,w-1) 1:(h,w+1) 2:(h-1,w) 3:(h+1,w), 0-pad OOB.
// ---------------------------------------------------------------------------
__device__ __forceinline__ void mix_one(const short8& a8, const short8& x8,
                                        const float* __restrict__ m, int c,
                                        unsigned short* __restrict__ o, size_t base)
{
  f32x4 c0 = *(const f32x4*)(m + c), c1 = *(const f32x4*)(m + c + 4);
  short8 r;
#pragma unroll
  for (int j = 0; j < 4; ++j) {
    r[j]     = (short)f2bf(bf2f((unsigned short)a8[j])     * c0[j] + bf2f((unsigned short)x8[j])     * (1.f - c0[j]));
    r[4 + j] = (short)f2bf(bf2f((unsigned short)a8[4 + j]) * c1[j] + bf2f((unsigned short)x8[4 + j]) * (1.f - c1[j]));
  }
  *(short8*)(o + base) = r;
}

template<int NOUT>
__global__ __launch_bounds__(256)
void mix_k(const unsigned short* __restrict__ xn,
           const float* __restrict__ m0, const float* __restrict__ m1, const float* __restrict__ m2,
           unsigned short* __restrict__ o0, unsigned short* __restrict__ o1, unsigned short* __restrict__ o2)
{
  const int tok = blockIdx.x * 4 + (threadIdx.x >> 6);
  const int lane = threadIdx.x & 63;
  const int t = tok % TT;
  const int h = t / WRES, w = t - h * WRES;
  const int grp = lane >> 4;                 // (lane*8)>>7
  const int dh = (grp == 2) ? -1 : (grp == 3) ? 1 : 0;
  const int dw = (grp == 0) ? -1 : (grp == 1) ? 1 : 0;
  const int sh = h + dh, sw = w + dw;
  const bool valid = ((unsigned)sh < (unsigned)HRES) && ((unsigned)sw < (unsigned)WRES);
  const size_t base = (size_t)tok * CD + lane * 8;
  short8 a8 = *(const short8*)(xn + base);
  short8 x8 = {0, 0, 0, 0, 0, 0, 0, 0};
  if (valid) {
    const unsigned short* src = xn + base;
    src += (ptrdiff_t)(dh * WRES + dw) * CD;
    x8 = *(const short8*)src;
  }
  const int c = lane * 8;
  mix_one(a8, x8, m0, c, o0, base);
  if (NOUT >= 2) mix_one(a8, x8, m1, c, o1, base);
  if (NOUT >= 3) mix_one(a8, x8, m2, c, o2, base);
}

// ---------------------------------------------------------------------------
// WKV fused chunked scan — single kernel, k/v read ONCE.
// Block = 800 threads = 25 chunks x 32 (b,c)-chains. Thread (chunk = t>>5,
// i = t&31) owns chunk `chunk` of chain bc = blk*32+i.
// Phase 1: chunk-local (aa,bb,pp) with exact reference update, caching the
//   25 (k,v) bf16 pairs packed in 25 VGPRs (fully unrolled -> static index).
// LDS summaries + barrier. Phase 2: fold prefix over chunks < own (identical
//   arithmetic to verified round-7 fold), then replay from cached k/v, emit y.
// ---------------------------------------------------------------------------
__global__ __launch_bounds__(800)
void wkv_fused(const unsigned short* __restrict__ kk, const unsigned short* __restrict__ vv,
               const float* __restrict__ sd, const float* __restrict__ sf,
               unsigned short* __restrict__ y)
{
  __shared__ float lA[NCH][NBC], lB[NCH][NBC], lP[NCH][NBC];
  const int t = threadIdx.x;            // 0..799
  const int chunk = t >> 5, i = t & 31;
  const int bc = blockIdx.x * NBC + i;  // 0..16383
  const int b = bc >> 9, c = bc & 511;
  const float w = sd[c] * (1.f / 625.f);
  const float u = sf[c] * (1.f / 625.f);
  const float lw = sd[c] * ((float)CLEN / 625.f);
  const size_t base = (size_t)b * TT * CD + (size_t)(chunk * CLEN) * CD + c;

  unsigned int kvc[CLEN];               // packed bf16: hi=k, lo=v
  float aa = 0.f, bb = 0.f, pp = -1e38f;
#pragma unroll
  for (int s = 0; s < CLEN; ++s) {
    const size_t o = base + (size_t)s * CD;
    unsigned short kh = kk[o], vh = vv[o];
    kvc[s] = ((unsigned int)kh << 16) | (unsigned int)vh;
    float kt = bf2f(kh), vt = bf2f(vh);
    float ww2 = pp + w;
    float p2 = fmaxf(ww2, kt);
    float e1 = __expf(ww2 - p2), e2 = __expf(kt - p2);
    aa = e1 * aa + e2 * vt;
    bb = e1 * bb + e2;
    pp = p2;
  }
  lA[chunk][i] = aa; lB[chunk][i] = bb; lP[chunk][i] = pp;
  __syncthreads();

  // fold prefix over chunks < chunk (exclusive)
  aa = 0.f; bb = 0.f; pp = -1e38f;
  for (int ch = 0; ch < chunk; ++ch) {
    float Ac = lA[ch][i], Bc = lB[ch][i], Pc = lP[ch][i];
    float pl = pp + lw;
    float pn = fmaxf(pl, Pc);
    float e1 = __expf(pl - pn), e2 = __expf(Pc - pn);
    aa = e1 * aa + e2 * Ac;
    bb = e1 * bb + e2 * Bc;
    pp = pn;
  }

  // replay exact reference steps from cached k/v
#pragma unroll
  for (int s = 0; s < CLEN; ++s) {
    const size_t o = base + (size_t)s * CD;
    const unsigned int pk = kvc[s];
    float kt = bf2f((unsigned short)(pk >> 16));
    float vt = bf2f((unsigned short)(pk & 0xffffu));
    float ww = u + kt;
    float p = fmaxf(pp, ww);
    float e1 = __expf(pp - p), e2 = __expf(ww - p);
    y[o] = f2bf((e1 * aa + e2 * vt) / (e1 * bb + e2));
    float ww2 = pp + w;
    float p2 = fmaxf(ww2, kt);
    float e1b = __expf(ww2 - p2), e2b = __expf(kt - p2);
    aa = e1b * aa + e2b * vt;
    bb = e1b * bb + e2b;
    pp = p2;
  }
}

// ---------------------------------------------------------------------------
// Weight transpose+convert: src f32 [R][C] -> dst bf16 [C][R]. 64x64 tiles.
// ---------------------------------------------------------------------------
struct TransDesc {
  const float* src[7];
  unsigned short* dst[7];
  int R[7]; int Cc[7];
  int toff[8];
};

__global__ __launch_bounds__(256)
void wtrans_k(TransDesc d)
{
  __shared__ float tile[64][65];
  const int bid = blockIdx.x;
  int mi = 0;
#pragma unroll
  for (int i = 0; i < 6; ++i) if (bid >= d.toff[i + 1]) mi = i + 1;
  const int t = bid - d.toff[mi];
  const int R = d.R[mi], Cc = d.Cc[mi];
  const int ct = Cc >> 6;
  const int tr = t / ct;
  const int r0 = tr << 6, c0 = (t - tr * ct) << 6;
  const float* src = d.src[mi];
  unsigned short* dst = d.dst[mi];
  const int rr = threadIdx.x >> 6, cc = threadIdx.x & 63;
#pragma unroll
  for (int i = 0; i < 16; ++i) {
    int r = i * 4 + rr;
    tile[cc][r] = src[(size_t)(r0 + r) * Cc + (c0 + cc)];
  }
  __syncthreads();
#pragma unroll
  for (int i = 0; i < 16; ++i) {
    int oc = i * 4 + rr;
    dst[(size_t)(c0 + oc) * R + (r0 + cc)] = f2bf(tile[oc][cc]);
  }
}

// ---------------------------------------------------------------------------
// Host launcher
// ---------------------------------------------------------------------------
extern "C" void kernel_launch(void* const* d_in, const int* in_sizes, int n_in,
                              void* d_out, int out_size, void* d_ws, size_t ws_size,
                              hipStream_t stream)
{
  const float* x    = (const float*)d_in[0];
  const float* g1   = (const float*)d_in[1];
  const float* b1   = (const float*)d_in[2];
  const float* g2   = (const float*)d_in[3];
  const float* b2   = (const float*)d_in[4];
  const float* sdec = (const float*)d_in[5];
  const float* sfir = (const float*)d_in[6];
  const float* smk  = (const float*)d_in[7];
  const float* smv  = (const float*)d_in[8];
  const float* smr  = (const float*)d_in[9];
  const float* Wk   = (const float*)d_in[10];
  const float* Wv   = (const float*)d_in[11];
  const float* Wr   = (const float*)d_in[12];
  const float* Wo   = (const float*)d_in[13];
  const float* kng  = (const float*)d_in[14];
  const float* knb  = (const float*)d_in[15];
  const float* cmk  = (const float*)d_in[16];
  const float* cmr  = (const float*)d_in[17];
  const float* Wkf  = (const float*)d_in[18];
  const float* Wvf  = (const float*)d_in[19];
  const float* Wrf  = (const float*)d_in[20];
  const float* cng  = (const float*)d_in[21];
  const float* cnb  = (const float*)d_in[22];

  // ---- workspace layout (193 MB, region-aliased, all activations bf16) ----
  char* ws = (char*)d_ws;
  unsigned short* kkbuf = (unsigned short*)(ws + 0);
  unsigned short* kbuf  = (unsigned short*)(ws + 0);
  unsigned short* vbuf  = (unsigned short*)(ws + 20480000);
  unsigned short* sr    = (unsigned short*)(ws + 40960000);
  unsigned short* abuf  = (unsigned short*)(ws + 61440000);
  unsigned short* xn    = (unsigned short*)(ws + 82837504);
  unsigned short* hn    = xn;
  unsigned short* rffn  = xn;
  unsigned short* xk    = (unsigned short*)(ws + 103546880);
  unsigned short* asr   = xk;
  unsigned short* xv    = (unsigned short*)(ws + 124256256);
  unsigned short* xk2   = xv;
  unsigned short* xr    = (unsigned short*)(ws + 144965632);
  unsigned short* xr2   = xr;
  unsigned short* x1    = (unsigned short*)(ws + 165675008);
  unsigned short* WkT   = (unsigned short*)(ws + 186155008);
  unsigned short* WvT   = WkT + 262144;
  unsigned short* WrT   = WvT + 262144;
  unsigned short* WoT   = WrT + 262144;
  unsigned short* WkfT  = WoT + 262144;   // [2048][512]
  unsigned short* WrfT  = WkfT + 1048576; // [512][512]
  unsigned short* WvfT  = WrfT + 262144;  // [512][2048]

  // 1. weight transpose/convert
  TransDesc td;
  const float* wsrc[7]   = {Wk, Wv, Wr, Wo, Wkf, Wrf, Wvf};
  unsigned short* wdst[7]= {WkT, WvT, WrT, WoT, WkfT, WrfT, WvfT};
  const int Rr[7]  = {512, 512, 512, 512, 512, 512, 2048};
  const int Ccc[7] = {512, 512, 512, 512, 2048, 512, 512};
  td.toff[0] = 0;
  for (int i = 0; i < 7; ++i) {
    td.src[i] = wsrc[i]; td.dst[i] = wdst[i]; td.R[i] = Rr[i]; td.Cc[i] = Ccc[i];
    td.toff[i + 1] = td.toff[i] + (Rr[i] / 64) * (Ccc[i] / 64);
  }
  wtrans_k<<<td.toff[7], 256, 0, stream>>>(td);

  // 2. xn = LN(x, g1, b1)
  ln512_k<0, 0><<<5000, 256, 0, stream>>>(x, g1, b1, nullptr, xn);
  // 3. xk/xv/xr = mix(xn, shift(xn))
  mix_k<3><<<5000, 256, 0, stream>>>(xn, smk, smv, smr, xk, xv, xr);
  // 4. k, v (bf16), sr = sigmoid(xr@Wr) (bf16) — one dispatch
  QkvArgs qa = {xk, xv, xr, WkT, WvT, WrT, kbuf, vbuf, sr};
  gemm_qkv<<<1884, 256, 0, stream>>>(qa);
  // 5. WKV fused chunked scan (single pass over k/v)
  wkv_fused<<<512, 800, 0, stream>>>(kbuf, vbuf, sdec, sfir, abuf);
  // 6. asr = LN(a, kn_g, kn_b) * sr
  ln512_k<1, 1><<<5000, 256, 0, stream>>>(abuf, kng, knb, sr, asr);
  // 7. x1 = bf16(x + asr@Wo)
  gemm_one<3><<<628, 256, 0, stream>>>(asr, WoT, MT, 512, 512, nullptr, x1, x, nullptr, nullptr);
  // 8. hn = LN(x1, g2, b2)
  ln512_k<0, 1><<<5000, 256, 0, stream>>>(x1, g2, b2, nullptr, hn);
  // 9. xk2/xr2 = mix(hn, shift(hn))
  mix_k<2><<<5000, 256, 0, stream>>>(hn, cmk, cmr, nullptr, xk2, xr2, nullptr);
  // 10. kk = relu^2(xk2@Wk_ffn), rffn = sigmoid(xr2@Wr_ffn) — one dispatch
  FfnArgs fa = {xk2, xr2, WkfT, WrfT, kkbuf, rffn};
  gemm_ffn<<<3140, 256, 0, stream>>>(fa);
  // 11. kk = LN(kk, cn_g, cn_b), in place
  ln2048_k<<<5000, 256, 0, stream>>>(kkbuf, cng, cnb);
  // 12. out = bf(x1) + bf(rffn) * (kk@Wv_ffn), f32
  gemm_one<4><<<628, 256, 0, stream>>>(kkbuf, WvfT, MT, 512, 2048, (float*)d_out, nullptr, nullptr, x1, rffn);
}

// Round 11
// 366.000 us; speedup vs baseline: 1.1628x; 1.1628x over previous
//
#include <hip/hip_runtime.h>
#include <cstdint>
#include <cstddef>

// Problem constants
#define HRES 25
#define WRES 25
#define NBATCH 32
#define TT 625            // tokens per image
#define CD 512            // channels
#define MT 20000          // total tokens = 32*625
#define HD 2048           // FFN hidden
#define NCH 25            // scan chunks
#define CLEN 25           // chunk length (NCH*CLEN == TT)

typedef __attribute__((ext_vector_type(8))) short short8;
typedef __attribute__((ext_vector_type(4))) float f32x4;

typedef const __attribute__((address_space(1))) void* as1cv;
typedef __attribute__((address_space(3))) void* as3v;

__device__ __forceinline__ float bf2f(unsigned short h){
  union { unsigned int u; float f; } w; w.u = ((unsigned int)h) << 16; return w.f;
}
__device__ __forceinline__ unsigned short f2bf(float f){
  union { float f; unsigned int u; } w; w.f = f;
  unsigned int u = w.u + 0x7fffu + ((w.u >> 16) & 1u);
  return (unsigned short)(u >> 16);
}

// XCD-chunked bijective block swizzle (m204): physical block b (round-robins
// XCD = b%8) -> logical tile id contiguous per XCD. Improves per-XCD L2 reuse
// of shared A-row-tiles / B-col-panels.
__device__ __forceinline__ int xcd_swz(int b, int nwg){
  const int q = nwg >> 3, r = nwg & 7;
  const int x = b & 7;
  const int base = (x < r) ? x * (q + 1) : r * (q + 1) + (x - r) * q;
  return base + (b >> 3);
}

// ---------------------------------------------------------------------------
// GEMM core: C[M,N] = A[M,K](bf16) @ Bt[N,K](bf16).  (verified round-3 m97
// structure: 128x128 tile, BK=64, 4 waves 2x2, global_load_lds width-16,
// XOR-swizzled LDS; ~3 blocks/CU give implicit wave-level overlap.)
// EPI: 1 = sigmoid->bf16; 2 = relu^2->bf16; 3 = f2bf(auxf + acc)->bf16;
//      4 = bf(auxb1) + bf(auxb2)*acc -> f32; 5 = plain bf16
// ---------------------------------------------------------------------------
template<int EPI>
__device__ __forceinline__ void gemm_core(short* As, short* Bs,
    const unsigned short* __restrict__ A, const unsigned short* __restrict__ Bt,
    int M, int N, int K, int bid,
    float* __restrict__ Cf, unsigned short* __restrict__ Cb,
    const float* __restrict__ auxf,
    const unsigned short* __restrict__ auxb1, const unsigned short* __restrict__ auxb2)
{
  const int ntile = N >> 7;
  const int tm = bid / ntile;
  const int tn = bid - tm * ntile;
  const int row0 = tm << 7, col0 = tn << 7;
  const int tid = threadIdx.x;
  const int wave = tid >> 6, lane = tid & 63;
  const int wm = wave >> 1, wn = wave & 1;

  const f32x4 fzero = {0.f, 0.f, 0.f, 0.f};
  f32x4 acc[4][4];
#pragma unroll
  for (int m = 0; m < 4; ++m)
#pragma unroll
    for (int n = 0; n < 4; ++n) acc[m][n] = fzero;

  // staging geometry: chunk = 16B unit; physical chunk p holds logical col (p&7)^(row&7)
  int sr_[4], sc_[4];
#pragma unroll
  for (int s = 0; s < 4; ++s) {
    int chunk = (wave * 4 + s) * 64 + lane;   // 0..1023
    sr_[s] = chunk >> 3;                      // tile row 0..127
    sc_[s] = (chunk & 7) ^ (sr_[s] & 7);      // logical k-chunk to fetch
  }

  for (int k0 = 0; k0 < K; k0 += 64) {
#pragma unroll
    for (int s = 0; s < 4; ++s) {
      const unsigned short* ga = A  + (size_t)(row0 + sr_[s]) * K + (k0 + sc_[s] * 8);
      const unsigned short* gb = Bt + (size_t)(col0 + sr_[s]) * K + (k0 + sc_[s] * 8);
      __builtin_amdgcn_global_load_lds((as1cv)ga, (as3v)(&As[(wave * 4 + s) * 512]), 16, 0, 0);
      __builtin_amdgcn_global_load_lds((as1cv)gb, (as3v)(&Bs[(wave * 4 + s) * 512]), 16, 0, 0);
    }
    __syncthreads();
#pragma unroll
    for (int kh = 0; kh < 2; ++kh) {
      const int cb = kh * 4 + (lane >> 4);    // logical k-chunk for this quarter-wave
      short8 af[4], bfv[4];
#pragma unroll
      for (int m = 0; m < 4; ++m) {
        int r = wm * 64 + m * 16 + (lane & 15);
        af[m] = *(const short8*)&As[r * 64 + ((cb ^ (r & 7)) << 3)];
      }
#pragma unroll
      for (int n = 0; n < 4; ++n) {
        int r = wn * 64 + n * 16 + (lane & 15);
        bfv[n] = *(const short8*)&Bs[r * 64 + ((cb ^ (r & 7)) << 3)];
      }
#pragma unroll
      for (int m = 0; m < 4; ++m)
#pragma unroll
        for (int n = 0; n < 4; ++n)
          acc[m][n] = __builtin_amdgcn_mfma_f32_16x16x32_bf16(af[m], bfv[n], acc[m][n], 0, 0, 0);
    }
    __syncthreads();
  }

  // C/D layout: col = lane&15, row = (lane>>4)*4 + j   [measured m89]
  const int gr0 = row0 + wm * 64 + ((lane >> 4) << 2);
  const int gc0 = col0 + wn * 64 + (lane & 15);
#pragma unroll
  for (int m = 0; m < 4; ++m) {
#pragma unroll
    for (int n = 0; n < 4; ++n) {
      const int gc = gc0 + n * 16;
#pragma unroll
      for (int j = 0; j < 4; ++j) {
        const int gr = gr0 + m * 16 + j;
        if (gr < M) {
          float val = acc[m][n][j];
          size_t idx = (size_t)gr * N + gc;
          if (EPI == 1) Cb[idx] = f2bf(1.f / (1.f + __expf(-val)));
          else if (EPI == 2) { float r = val > 0.f ? val : 0.f; Cb[idx] = f2bf(r * r); }
          else if (EPI == 3) Cb[idx] = f2bf(auxf[idx] + val);
          else if (EPI == 4) Cf[idx] = bf2f(auxb1[idx]) + bf2f(auxb2[idx]) * val;
          else if (EPI == 5) Cb[idx] = f2bf(val);
        }
      }
    }
  }
}

template<int EPI>
__global__ __launch_bounds__(256, 2)
void gemm_one(const unsigned short* __restrict__ A, const unsigned short* __restrict__ Bt,
              int M, int N, int K,
              float* __restrict__ Cf, unsigned short* __restrict__ Cb,
              const float* __restrict__ auxf,
              const unsigned short* __restrict__ auxb1, const unsigned short* __restrict__ auxb2)
{
  __shared__ short As[8192];
  __shared__ short Bs[8192];
  const int bid = xcd_swz(blockIdx.x, gridDim.x);
  gemm_core<EPI>(As, Bs, A, Bt, M, N, K, bid, Cf, Cb, auxf, auxb1, auxb2);
}

// batched QKV: seg 0: k = xk@WkT (bf16), seg 1: v = xv@WvT (bf16), seg 2: sr = sigmoid(xr@WrT)
struct QkvArgs {
  const unsigned short *xk, *xv, *xr, *WkT, *WvT, *WrT;
  unsigned short *k, *v, *sr;
};
__global__ __launch_bounds__(256, 2)
void gemm_qkv(QkvArgs a)
{
  __shared__ short As[8192];
  __shared__ short Bs[8192];
  const int bid = xcd_swz(blockIdx.x, gridDim.x);
  if (bid < 628)
    gemm_core<5>(As, Bs, a.xk, a.WkT, MT, 512, 512, bid, nullptr, a.k, nullptr, nullptr, nullptr);
  else if (bid < 1256)
    gemm_core<5>(As, Bs, a.xv, a.WvT, MT, 512, 512, bid - 628, nullptr, a.v, nullptr, nullptr, nullptr);
  else
    gemm_core<1>(As, Bs, a.xr, a.WrT, MT, 512, 512, bid - 1256, nullptr, a.sr, nullptr, nullptr, nullptr);
}

// batched FFN: seg 0 (2512 blocks): kk = relu^2(xk2@WkfT) N=2048; seg 1 (628): rffn = sigmoid(xr2@WrfT)
struct FfnArgs {
  const unsigned short *xk2, *xr2, *Wkf, *Wrf;
  unsigned short *kk, *rf;
};
__global__ __launch_bounds__(256, 2)
void gemm_ffn(FfnArgs a)
{
  __shared__ short As[8192];
  __shared__ short Bs[8192];
  const int bid = xcd_swz(blockIdx.x, gridDim.x);
  if (bid < 2512)
    gemm_core<2>(As, Bs, a.xk2, a.Wkf, MT, 2048, 512, bid, nullptr, a.kk, nullptr, nullptr, nullptr);
  else
    gemm_core<1>(As, Bs, a.xr2, a.Wrf, MT, 512, 512, bid - 2512, nullptr, a.rf, nullptr, nullptr, nullptr);
}

// ---------------------------------------------------------------------------
// LayerNorm over 512 -> bf16 out. One wave per token, 4 tokens/block.
// MODE 0: out = LN(in)*g+b ; MODE 1: out = (LN(in)*g+b) * bf(mul)
// BIN 0: f32 input ; BIN 1: bf16 input
// ---------------------------------------------------------------------------
template<int MODE, int BIN>
__global__ __launch_bounds__(256)
void ln512_k(const void* __restrict__ inv, const float* __restrict__ gw, const float* __restrict__ bw,
             const unsigned short* __restrict__ mul, unsigned short* __restrict__ out)
{
  const int tok = blockIdx.x * 4 + (threadIdx.x >> 6);
  const int lane = threadIdx.x & 63;
  const size_t base = (size_t)tok * CD + lane * 8;
  f32x4 v0, v1;
  if (BIN) {
    short8 h = *(const short8*)((const unsigned short*)inv + base);
#pragma unroll
    for (int j = 0; j < 4; ++j) { v0[j] = bf2f((unsigned short)h[j]); v1[j] = bf2f((unsigned short)h[4 + j]); }
  } else {
    v0 = *(const f32x4*)((const float*)inv + base);
    v1 = *(const f32x4*)((const float*)inv + base + 4);
  }
  float s = (v0[0] + v0[1]) + (v0[2] + v0[3]) + (v1[0] + v1[1]) + (v1[2] + v1[3]);
#pragma unroll
  for (int o = 32; o; o >>= 1) s += __shfl_xor(s, o, 64);
  const float mean = s * (1.f / 512.f);
  float q = 0.f;
#pragma unroll
  for (int j = 0; j < 4; ++j) { float d = v0[j] - mean; q += d * d; d = v1[j] - mean; q += d * d; }
#pragma unroll
  for (int o = 32; o; o >>= 1) q += __shfl_xor(q, o, 64);
  const float rstd = rsqrtf(q * (1.f / 512.f) + 1e-5f);
  const int c = lane * 8;
  f32x4 ga = *(const f32x4*)(gw + c), gb = *(const f32x4*)(gw + c + 4);
  f32x4 ba = *(const f32x4*)(bw + c), bb = *(const f32x4*)(bw + c + 4);
  float mv[8];
  if (MODE == 1) {
    short8 m8 = *(const short8*)(mul + base);
#pragma unroll
    for (int j = 0; j < 8; ++j) mv[j] = bf2f((unsigned short)m8[j]);
  }
  short8 o8;
#pragma unroll
  for (int j = 0; j < 4; ++j) {
    float r0 = (v0[j] - mean) * rstd * ga[j] + ba[j];
    float r1 = (v1[j] - mean) * rstd * gb[j] + bb[j];
    if (MODE == 1) { r0 *= mv[j]; r1 *= mv[4 + j]; }
    o8[j]     = (short)f2bf(r0);
    o8[4 + j] = (short)f2bf(r1);
  }
  *(short8*)(out + base) = o8;
}

// LayerNorm over 2048 bf16, in-place. One wave per token, 4 tokens/block.
__global__ __launch_bounds__(256)
void ln2048_k(unsigned short* __restrict__ buf, const float* __restrict__ gw, const float* __restrict__ bw)
{
  const int tok = blockIdx.x * 4 + (threadIdx.x >> 6);
  const int lane = threadIdx.x & 63;
  unsigned short* p = buf + (size_t)tok * HD;
  float vals[32];
  float s = 0.f;
#pragma unroll
  for (int jb = 0; jb < 4; ++jb) {
    short8 h = *(const short8*)(p + jb * 512 + lane * 8);
#pragma unroll
    for (int j = 0; j < 8; ++j) { float f = bf2f((unsigned short)h[j]); vals[jb * 8 + j] = f; s += f; }
  }
#pragma unroll
  for (int o = 32; o; o >>= 1) s += __shfl_xor(s, o, 64);
  const float mean = s * (1.f / 2048.f);
  float q = 0.f;
#pragma unroll
  for (int i = 0; i < 32; ++i) { float d = vals[i] - mean; q += d * d; }
#pragma unroll
  for (int o = 32; o; o >>= 1) q += __shfl_xor(q, o, 64);
  const float rstd = rsqrtf(q * (1.f / 2048.f) + 1e-5f);
#pragma unroll
  for (int jb = 0; jb < 4; ++jb) {
    const int c = jb * 512 + lane * 8;
    f32x4 ga = *(const f32x4*)(gw + c), gb = *(const f32x4*)(gw + c + 4);
    f32x4 ba = *(const f32x4*)(bw + c), bb = *(const f32x4*)(bw + c + 4);
    short8 o8;
#pragma unroll
    for (int j = 0; j < 4; ++j) {
      o8[j]     = (short)f2bf((vals[jb * 8 + j]     - mean) * rstd * ga[j] + ba[j]);
      o8[4 + j] = (short)f2bf((vals[jb * 8 + 4 + j] - mean) * rstd * gb[j] + bb[j]);
    }
    *(short8*)(p + c) = o8;
  }
}

// ---------------------------------------------------------------------------
// q_shift + token-mix: out_i = xn*m_i + xx*(1-m_i). 4 tokens per 256-thr block.
// channel group g = c>>7 : 0:(h,w-1) 1:(h,w+1) 2:(h-1,w) 3:(h+1,w), 0-pad OOB.
// ---------------------------------------------------------------------------
__device__ __forceinline__ void mix_one(const short8& a8, const short8& x8,
                                        const float* __restrict__ m, int c,
                                        unsigned short* __restrict__ o, size_t base)
{
  f32x4 c0 = *(const f32x4*)(m + c), c1 = *(const f32x4*)(m + c + 4);
  short8 r;
#pragma unroll
  for (int j = 0; j < 4; ++j) {
    r[j]     = (short)f2bf(bf2f((unsigned short)a8[j])     * c0[j] + bf2f((unsigned short)x8[j])     * (1.f - c0[j]));
    r[4 + j] = (short)f2bf(bf2f((unsigned short)a8[4 + j]) * c1[j] + bf2f((unsigned short)x8[4 + j]) * (1.f - c1[j]));
  }
  *(short8*)(o + base) = r;
}

template<int NOUT>
__global__ __launch_bounds__(256)
void mix_k(const unsigned short* __restrict__ xn,
           const float* __restrict__ m0, const float* __restrict__ m1, const float* __restrict__ m2,
           unsigned short* __restrict__ o0, unsigned short* __restrict__ o1, unsigned short* __restrict__ o2)
{
  const int tok = blockIdx.x * 4 + (threadIdx.x >> 6);
  const int lane = threadIdx.x & 63;
  const int t = tok % TT;
  const int h = t / WRES, w = t - h * WRES;
  const int grp = lane >> 4;                 // (lane*8)>>7
  const int dh = (grp == 2) ? -1 : (grp == 3) ? 1 : 0;
  const int dw = (grp == 0) ? -1 : (grp == 1) ? 1 : 0;
  const int sh = h + dh, sw = w + dw;
  const bool valid = ((unsigned)sh < (unsigned)HRES) && ((unsigned)sw < (unsigned)WRES);
  const size_t base = (size_t)tok * CD + lane * 8;
  short8 a8 = *(const short8*)(xn + base);
  short8 x8 = {0, 0, 0, 0, 0, 0, 0, 0};
  if (valid) {
    const unsigned short* src = xn + base;
    src += (ptrdiff_t)(dh * WRES + dw) * CD;
    x8 = *(const short8*)src;
  }
  const int c = lane * 8;
  mix_one(a8, x8, m0, c, o0, base);
  if (NOUT >= 2) mix_one(a8, x8, m1, c, o1, base);
  if (NOUT >= 3) mix_one(a8, x8, m2, c, o2, base);
}

// ---------------------------------------------------------------------------
// WKV chunked parallel scan (bf16 k/v in, bf16 y out, f32 state).
// ---------------------------------------------------------------------------
__global__ __launch_bounds__(256)
void wkv_sum(const unsigned short* __restrict__ kk, const unsigned short* __restrict__ vv,
             const float* __restrict__ sd,
             float* __restrict__ sA, float* __restrict__ sB, float* __restrict__ sP)
{
  const int tid = blockIdx.x * 256 + threadIdx.x;   // 0..409599
  const int chunk = tid >> 14;                      // /16384
  const int bc = tid & 16383;
  const int b = bc >> 9, c = bc & 511;
  const float w = sd[c] * (1.f / 625.f);
  const size_t base = (size_t)b * TT * CD + (size_t)(chunk * CLEN) * CD + c;
  float aa = 0.f, bb = 0.f, pp = -1e38f;
  for (int t = 0; t < CLEN; ++t) {
    const size_t o = base + (size_t)t * CD;
    float kt = bf2f(kk[o]), vt = bf2f(vv[o]);
    float ww2 = pp + w;
    float p2 = fmaxf(ww2, kt);
    float e1 = __expf(ww2 - p2), e2 = __expf(kt - p2);
    aa = e1 * aa + e2 * vt;
    bb = e1 * bb + e2;
    pp = p2;
  }
  sA[tid] = aa; sB[tid] = bb; sP[tid] = pp;
}

__global__ __launch_bounds__(256)
void wkv_comb(const float* __restrict__ sd,
              const float* __restrict__ sA, const float* __restrict__ sB, const float* __restrict__ sP,
              float* __restrict__ pA, float* __restrict__ pB, float* __restrict__ pP)
{
  const int bc = blockIdx.x * 256 + threadIdx.x;    // 0..16383
  const int c = bc & 511;
  const float lw = sd[c] * ((float)CLEN / 625.f);
  float aa = 0.f, bb = 0.f, pp = -1e38f;
  for (int i = 0; i < NCH; ++i) {
    const int idx = i * 16384 + bc;
    pA[idx] = aa; pB[idx] = bb; pP[idx] = pp;       // prefix BEFORE chunk i
    float Ac = sA[idx], Bc = sB[idx], Pc = sP[idx];
    float pl = pp + lw;
    float pn = fmaxf(pl, Pc);
    float e1 = __expf(pl - pn), e2 = __expf(Pc - pn);
    aa = e1 * aa + e2 * Ac;
    bb = e1 * bb + e2 * Bc;
    pp = pn;
  }
}

__global__ __launch_bounds__(256)
void wkv_out(const unsigned short* __restrict__ kk, const unsigned short* __restrict__ vv,
             const float* __restrict__ sd, const float* __restrict__ sf,
             const float* __restrict__ pA, const float* __restrict__ pB, const float* __restrict__ pP,
             unsigned short* __restrict__ y)
{
  const int tid = blockIdx.x * 256 + threadIdx.x;   // 0..409599
  const int chunk = tid >> 14;
  const int bc = tid & 16383;
  const int b = bc >> 9, c = bc & 511;
  const float w = sd[c] * (1.f / 625.f);
  const float u = sf[c] * (1.f / 625.f);
  const size_t base = (size_t)b * TT * CD + (size_t)(chunk * CLEN) * CD + c;
  float aa = pA[tid], bb = pB[tid], pp = pP[tid];
  for (int t = 0; t < CLEN; ++t) {
    const size_t o = base + (size_t)t * CD;
    float kt = bf2f(kk[o]), vt = bf2f(vv[o]);
    float ww = u + kt;
    float p = fmaxf(pp, ww);
    float e1 = __expf(pp - p), e2 = __expf(ww - p);
    y[o] = f2bf((e1 * aa + e2 * vt) / (e1 * bb + e2));
    float ww2 = pp + w;
    float p2 = fmaxf(ww2, kt);
    float e1b = __expf(ww2 - p2), e2b = __expf(kt - p2);
    aa = e1b * aa + e2b * vt;
    bb = e1b * bb + e2b;
    pp = p2;
  }
}

// ---------------------------------------------------------------------------
// Weight transpose+convert: src f32 [R][C] -> dst bf16 [C][R]. 64x64 tiles.
// ---------------------------------------------------------------------------
struct TransDesc {
  const float* src[7];
  unsigned short* dst[7];
  int R[7]; int Cc[7];
  int toff[8];
};

__global__ __launch_bounds__(256)
void wtrans_k(TransDesc d)
{
  __shared__ float tile[64][65];
  const int bid = blockIdx.x;
  int mi = 0;
#pragma unroll
  for (int i = 0; i < 6; ++i) if (bid >= d.toff[i + 1]) mi = i + 1;
  const int t = bid - d.toff[mi];
  const int R = d.R[mi], Cc = d.Cc[mi];
  const int ct = Cc >> 6;
  const int tr = t / ct;
  const int r0 = tr << 6, c0 = (t - tr * ct) << 6;
  const float* src = d.src[mi];
  unsigned short* dst = d.dst[mi];
  const int rr = threadIdx.x >> 6, cc = threadIdx.x & 63;
#pragma unroll
  for (int i = 0; i < 16; ++i) {
    int r = i * 4 + rr;
    tile[cc][r] = src[(size_t)(r0 + r) * Cc + (c0 + cc)];
  }
  __syncthreads();
#pragma unroll
  for (int i = 0; i < 16; ++i) {
    int oc = i * 4 + rr;
    dst[(size_t)(c0 + oc) * R + (r0 + cc)] = f2bf(tile[oc][cc]);
  }
}

// ---------------------------------------------------------------------------
// Host launcher
// ---------------------------------------------------------------------------
extern "C" void kernel_launch(void* const* d_in, const int* in_sizes, int n_in,
                              void* d_out, int out_size, void* d_ws, size_t ws_size,
                              hipStream_t stream)
{
  const float* x    = (const float*)d_in[0];
  const float* g1   = (const float*)d_in[1];
  const float* b1   = (const float*)d_in[2];
  const float* g2   = (const float*)d_in[3];
  const float* b2   = (const float*)d_in[4];
  const float* sdec = (const float*)d_in[5];
  const float* sfir = (const float*)d_in[6];
  const float* smk  = (const float*)d_in[7];
  const float* smv  = (const float*)d_in[8];
  const float* smr  = (const float*)d_in[9];
  const float* Wk   = (const float*)d_in[10];
  const float* Wv   = (const float*)d_in[11];
  const float* Wr   = (const float*)d_in[12];
  const float* Wo   = (const float*)d_in[13];
  const float* kng  = (const float*)d_in[14];
  const float* knb  = (const float*)d_in[15];
  const float* cmk  = (const float*)d_in[16];
  const float* cmr  = (const float*)d_in[17];
  const float* Wkf  = (const float*)d_in[18];
  const float* Wvf  = (const float*)d_in[19];
  const float* Wrf  = (const float*)d_in[20];
  const float* cng  = (const float*)d_in[21];
  const float* cnb  = (const float*)d_in[22];

  // ---- workspace layout (193 MB, region-aliased, all activations bf16) ----
  char* ws = (char*)d_ws;
  unsigned short* kkbuf = (unsigned short*)(ws + 0);
  unsigned short* kbuf  = (unsigned short*)(ws + 0);
  unsigned short* vbuf  = (unsigned short*)(ws + 20480000);
  unsigned short* sr    = (unsigned short*)(ws + 40960000);
  unsigned short* abuf  = (unsigned short*)(ws + 61440000);
  unsigned short* xn    = (unsigned short*)(ws + 82837504);
  unsigned short* hn    = xn;
  unsigned short* rffn  = xn;
  unsigned short* xk    = (unsigned short*)(ws + 103546880);
  unsigned short* asr   = xk;
  unsigned short* xv    = (unsigned short*)(ws + 124256256);
  unsigned short* xk2   = xv;
  unsigned short* xr    = (unsigned short*)(ws + 144965632);
  unsigned short* xr2   = xr;
  unsigned short* x1    = (unsigned short*)(ws + 165675008);
  unsigned short* WkT   = (unsigned short*)(ws + 186155008);
  unsigned short* WvT   = WkT + 262144;
  unsigned short* WrT   = WvT + 262144;
  unsigned short* WoT   = WrT + 262144;
  unsigned short* WkfT  = WoT + 262144;   // [2048][512]
  unsigned short* WrfT  = WkfT + 1048576; // [512][512]
  unsigned short* WvfT  = WrfT + 262144;  // [512][2048]

  // scan state: 6 x 409600 f32 = 9.83MB, aliased into xv region (dead then)
  float* sA = (float*)(ws + 124256256);
  float* sB = sA + 409600;
  float* sP = sB + 409600;
  float* pA = sP + 409600;
  float* pB = pA + 409600;
  float* pP = pB + 409600;

  // 1. weight transpose/convert
  TransDesc td;
  const float* wsrc[7]   = {Wk, Wv, Wr, Wo, Wkf, Wrf, Wvf};
  unsigned short* wdst[7]= {WkT, WvT, WrT, WoT, WkfT, WrfT, WvfT};
  const int Rr[7]  = {512, 512, 512, 512, 512, 512, 2048};
  const int Ccc[7] = {512, 512, 512, 512, 2048, 512, 512};
  td.toff[0] = 0;
  for (int i = 0; i < 7; ++i) {
    td.src[i] = wsrc[i]; td.dst[i] = wdst[i]; td.R[i] = Rr[i]; td.Cc[i] = Ccc[i];
    td.toff[i + 1] = td.toff[i] + (Rr[i] / 64) * (Ccc[i] / 64);
  }
  wtrans_k<<<td.toff[7], 256, 0, stream>>>(td);

  // 2. xn = LN(x, g1, b1)
  ln512_k<0, 0><<<5000, 256, 0, stream>>>(x, g1, b1, nullptr, xn);
  // 3. xk/xv/xr = mix(xn, shift(xn))
  mix_k<3><<<5000, 256, 0, stream>>>(xn, smk, smv, smr, xk, xv, xr);
  // 4. k, v (bf16), sr = sigmoid(xr@Wr) (bf16) — one dispatch
  QkvArgs qa = {xk, xv, xr, WkT, WvT, WrT, kbuf, vbuf, sr};
  gemm_qkv<<<1884, 256, 0, stream>>>(qa);
  // 5-7. WKV chunked scan (3 passes)
  wkv_sum<<<1600, 256, 0, stream>>>(kbuf, vbuf, sdec, sA, sB, sP);
  wkv_comb<<<64, 256, 0, stream>>>(sdec, sA, sB, sP, pA, pB, pP);
  wkv_out<<<1600, 256, 0, stream>>>(kbuf, vbuf, sdec, sfir, pA, pB, pP, abuf);
  // 8. asr = LN(a, kn_g, kn_b) * sr
  ln512_k<1, 1><<<5000, 256, 0, stream>>>(abuf, kng, knb, sr, asr);
  // 9. x1 = bf16(x + asr@Wo)
  gemm_one<3><<<628, 256, 0, stream>>>(asr, WoT, MT, 512, 512, nullptr, x1, x, nullptr, nullptr);
  // 10. hn = LN(x1, g2, b2)
  ln512_k<0, 1><<<5000, 256, 0, stream>>>(x1, g2, b2, nullptr, hn);
  // 11. xk2/xr2 = mix(hn, shift(hn))
  mix_k<2><<<5000, 256, 0, stream>>>(hn, cmk, cmr, nullptr, xk2, xr2, nullptr);
  // 12. kk = relu^2(xk2@Wk_ffn), rffn = sigmoid(xr2@Wr_ffn) — one dispatch
  FfnArgs fa = {xk2, xr2, WkfT, WrfT, kkbuf, rffn};
  gemm_ffn<<<3140, 256, 0, stream>>>(fa);
  // 13. kk = LN(kk, cn_g, cn_b), in place
  ln2048_k<<<5000, 256, 0, stream>>>(kkbuf, cng, cnb);
  // 14. rffn stays in xn region; out = bf(x1) + bf(rffn) * (kk@Wv_ffn), f32
  gemm_one<4><<<628, 256, 0, stream>>>(kkbuf, WvfT, MT, 512, 2048, (float*)d_out, nullptr, nullptr, x1, rffn);
}